// Round 5
// baseline (278.410 us; speedup 1.0000x reference)
//
#include <hip/hip_runtime.h>
#include <hip/hip_bf16.h>
#include <math.h>

// Problem constants: B=2, T=2048, M=1024, H=8, D=128
#define B_  2
#define T_  2048
#define M_  1024
#define H_  8
#define D_  128
#define NROW (B_ * T_)          // 4096
#define HD  (H_ * D_)           // 1024

#define NORM_EPS 1e-6f
#define QK_MULT  0.08838834764831845f   // sqrt(1/128)
#define LN_BASE_64 0.14391156510f       // ln(10000)/64

typedef short bf16x8  __attribute__((ext_vector_type(8)));    // 8 bf16 = 4 VGPRs
typedef float f32x4   __attribute__((ext_vector_type(4)));
typedef float f32x16  __attribute__((ext_vector_type(16)));
typedef unsigned int uint32x2 __attribute__((ext_vector_type(2)));

static __device__ __forceinline__ unsigned short f2bf(float f) {
    union { __hip_bfloat16 h; unsigned short u; } cv;
    cv.h = __float2bfloat16(f);
    return cv.u;
}
static __device__ __forceinline__ unsigned int pk2bf(float a, float b) {
    return ((unsigned int)f2bf(b) << 16) | f2bf(a);
}

// async global->LDS, 16 bytes per lane. LDS dest = wave-uniform base + lane*16.
static __device__ __forceinline__ void gload_lds16(const unsigned short* g,
                                                   unsigned short* l) {
    __builtin_amdgcn_global_load_lds(
        (const __attribute__((address_space(1))) void*)g,
        (__attribute__((address_space(3))) void*)l, 16, 0, 0);
}

// ---------------------------------------------------------------------------
// prep: z<4 -> transpose+cast weight z (out[n][k]=bf16(in[k][n]));
//       z==4 -> linear cast of x to bf16. Block (0,0,z=4) also zeroes the
//       256 flash split-tile arrival counters (in d_out, overwritten later
//       by gemm_out, so no extra workspace).
// ---------------------------------------------------------------------------
__global__ __launch_bounds__(256) void prep(const float* __restrict__ x,
                                            const float* __restrict__ w0,
                                            const float* __restrict__ w1,
                                            const float* __restrict__ w2,
                                            const float* __restrict__ w3,
                                            unsigned short* __restrict__ xb,
                                            unsigned short* __restrict__ wqkvT,
                                            unsigned short* __restrict__ woT,
                                            int* __restrict__ tctr)
{
    __shared__ float t[32][33];
    const int z = blockIdx.z;
    if (z == 4) {
        if (blockIdx.x == 0 && blockIdx.y == 0)
            tctr[threadIdx.x] = 0;               // 256 counters, 256 threads
        const size_t base = ((size_t)blockIdx.y * 32 + blockIdx.x) * 4096;
        #pragma unroll
        for (int it = 0; it < 4; ++it) {
            const size_t i = base + it * 1024 + threadIdx.x * 4;
            const float4 v = *(const float4*)(x + i);
            ushort4 o;
            o.x = f2bf(v.x); o.y = f2bf(v.y); o.z = f2bf(v.z); o.w = f2bf(v.w);
            *(ushort4*)(xb + i) = o;
        }
        return;
    }
    const float* in = z == 0 ? w0 : (z == 1 ? w1 : (z == 2 ? w2 : w3));
    unsigned short* out = z < 3 ? (wqkvT + (size_t)z * 1024 * 1024) : woT;

    const int tx = threadIdx.x & 31;
    const int ty = threadIdx.x >> 5;
    const int n0 = blockIdx.x * 32;
    const int k0 = blockIdx.y * 32;
    #pragma unroll
    for (int r = 0; r < 4; ++r)
        t[ty + r * 8][tx] = in[(size_t)(k0 + ty + r * 8) * 1024 + n0 + tx];
    __syncthreads();
    #pragma unroll
    for (int r = 0; r < 4; ++r)
        out[(size_t)(n0 + ty + r * 8) * 1024 + k0 + tx] = f2bf(t[tx][ty + r * 8]);
}

// ---------------------------------------------------------------------------
// QKV GEMM: C = A[4096x1024] * Bt[3072x1024]^T. 128x128 tile, BK=32,
// async double-buffered global_load_lds staging, 3 blocks/CU. V epilogue
// transposes via LDS so vt is written in contiguous 256-B rows (kills the
// ~24 MB write-allocate overfetch of the old 8-B/4-KB-stride scatter).
// ---------------------------------------------------------------------------
__global__ __launch_bounds__(256) void gemm_qkv(const unsigned short* __restrict__ A,
                                                const unsigned short* __restrict__ Bt,
                                                unsigned short* __restrict__ oq,
                                                unsigned short* __restrict__ ok,
                                                unsigned short* __restrict__ vt)
{
    __shared__ __align__(16) unsigned short smem[17408];   // 34 KB
    #define AsQ(buf) (smem + (buf) * 4096)
    #define BsQ(buf) (smem + 8192 + (buf) * 4096)

    const int tid  = threadIdx.x;
    const int lane = tid & 63;
    const int w    = tid >> 6;          // wave = row band (32 rows)
    const int g    = lane >> 4;
    const int lc   = lane & 15;

    const int m0 = blockIdx.y * 128;
    const int n0 = blockIdx.x * 128;

    const unsigned short* aBase = A  + (size_t)m0 * 1024;
    const unsigned short* bBase = Bt + (size_t)n0 * 1024;

    int dstOff[2];
    size_t srcOff[2];
    #pragma unroll
    for (int it = 0; it < 2; ++it) {
        const int u  = tid + it * 256;      // 0..511
        const int r2 = u >> 2;              // tile row
        const int sg = (u & 3) ^ (r2 & 3);  // src segment (XOR swizzle)
        dstOff[it] = u * 8;
        srcOff[it] = (size_t)r2 * 1024 + sg * 8;
    }

    f32x4 acc[2][8];
    #pragma unroll
    for (int i = 0; i < 2; ++i)
        #pragma unroll
        for (int j = 0; j < 8; ++j)
            acc[i][j] = (f32x4){0.f, 0.f, 0.f, 0.f};

    #pragma unroll
    for (int it = 0; it < 2; ++it) {
        gload_lds16(aBase + srcOff[it], AsQ(0) + dstOff[it]);
        gload_lds16(bBase + srcOff[it], BsQ(0) + dstOff[it]);
    }

    for (int kt = 0; kt < 32; ++kt) {
        const int cur = kt & 1;
        __syncthreads();                      // tile kt ready; buf^1 free

        if (kt < 31) {                        // async-prefetch next K-tile
            const int k0n = (kt + 1) * 32;
            #pragma unroll
            for (int it = 0; it < 2; ++it) {
                gload_lds16(aBase + srcOff[it] + k0n, AsQ(cur ^ 1) + dstOff[it]);
                gload_lds16(bBase + srcOff[it] + k0n, BsQ(cur ^ 1) + dstOff[it]);
            }
        }

        const int sw = (g ^ (lc & 3)) << 3;
        bf16x8 af[2], bfr[8];
        #pragma unroll
        for (int i = 0; i < 2; ++i)
            af[i] = *(const bf16x8*)&AsQ(cur)[(w * 32 + i * 16 + lc) * 32 + sw];
        #pragma unroll
        for (int j = 0; j < 8; ++j)
            bfr[j] = *(const bf16x8*)&BsQ(cur)[(j * 16 + lc) * 32 + sw];

        #pragma unroll
        for (int i = 0; i < 2; ++i)
            #pragma unroll
            for (int j = 0; j < 8; ++j)
                acc[i][j] = __builtin_amdgcn_mfma_f32_16x16x32_bf16(af[i], bfr[j], acc[i][j], 0, 0, 0);
    }

    const int which = n0 >> 10;
    const int ncol0 = n0 & 1023;            // head-aligned (tile = one head)
    if (which < 2) {
        // ---- fused RMSNorm + RoPE + sqrt(qk_scale) for q / k ----
        unsigned short* outp = which == 0 ? oq : ok;
        float freq[4];
        #pragma unroll
        for (int j = 0; j < 4; ++j)
            freq[j] = __expf(-(float)(j * 16 + lc) * LN_BASE_64);

        #pragma unroll
        for (int i = 0; i < 2; ++i)
            #pragma unroll
            for (int r = 0; r < 4; ++r) {
                float s = 0.f;
                #pragma unroll
                for (int j = 0; j < 8; ++j) s += acc[i][j][r] * acc[i][j][r];
                #pragma unroll
                for (int off = 1; off < 16; off <<= 1) s += __shfl_xor(s, off);
                const float rms = rsqrtf(s * (1.0f / 128.0f) + NORM_EPS) * QK_MULT;

                const int trow = m0 + w * 32 + i * 16 + g * 4 + r;
                const float tpos = (float)(trow & (T_ - 1));
                unsigned short* op = outp + (size_t)trow * 1024 + ncol0;
                #pragma unroll
                for (int j = 0; j < 4; ++j) {
                    float sn, cs;
                    __sincosf(tpos * freq[j], &sn, &cs);
                    const float e = acc[i][j][r] * rms;       // even half
                    const float o = acc[i][j + 4][r] * rms;   // odd half (+64)
                    op[j * 16 + lc]      = f2bf(e * cs - o * sn);
                    op[j * 16 + lc + 64] = f2bf(e * sn + o * cs);
                }
            }
    } else {
        // V: transpose in LDS, then dump contiguous 256-B rows ->
        // vt[(b*8+h)*128 + d][t]. Full-line writes, no write-allocate RMW.
        const int b2 = m0 >> 11;
        const int hh = ncol0 >> 7;
        const int PAD = 136;                 // 272 B rows: 16-B aligned, odd*16
        __syncthreads();                     // staging reads done; reuse smem
        #pragma unroll
        for (int i = 0; i < 2; ++i) {
            const int t0 = w * 32 + i * 16 + g * 4;
            #pragma unroll
            for (int j = 0; j < 8; ++j) {
                uint2 val;
                val.x = pk2bf(acc[i][j][0], acc[i][j][1]);
                val.y = pk2bf(acc[i][j][2], acc[i][j][3]);
                *(uint2*)&smem[(j * 16 + lc) * PAD + t0] = val;
            }
        }
        __syncthreads();
        const int row  = tid >> 1;           // d (0..127)
        const int half = tid & 1;            // t half (64 shorts)
        const unsigned short* src = &smem[row * PAD + half * 64];
        unsigned short* dst = vt + ((size_t)(b2 * 8 + hh) * 128 + row) * T_
                                 + (m0 & 2047) + half * 64;
        #pragma unroll
        for (int it2 = 0; it2 < 8; ++it2)
            *(uint4*)(dst + it2 * 8) = *(const uint4*)(src + it2 * 8);
    }
    #undef AsQ
    #undef BsQ
}

// ---------------------------------------------------------------------------
// Output projection: C[4096x1024] fp32 = A * Bt^T. 128x64 tile (512 blocks,
// 3/CU, all resident), BK=64, async double-buffered staging + XOR swizzle.
// 2x2 waves of 64x32.
// ---------------------------------------------------------------------------
__global__ __launch_bounds__(256) void gemm_out(const unsigned short* __restrict__ A,
                                                const unsigned short* __restrict__ Bt,
                                                float* __restrict__ cf)
{
    __shared__ unsigned short As[2][128 * 64];   // 2 x 16 KB
    __shared__ unsigned short Bs[2][64 * 64];    // 2 x 8 KB  (48 KB total)

    const int tid  = threadIdx.x;
    const int lane = tid & 63;
    const int w    = tid >> 6;
    const int g    = lane >> 4;
    const int lc   = lane & 15;
    const int wm   = w >> 1;
    const int wn   = w & 1;

    const int m0 = blockIdx.y * 128;
    const int n0 = blockIdx.x * 64;

    const unsigned short* aBase = A  + (size_t)m0 * 1024;
    const unsigned short* bBase = Bt + (size_t)n0 * 1024;

    int dstA[4], dstB[2];
    size_t srcA[4], srcB[2];
    #pragma unroll
    for (int it = 0; it < 4; ++it) {
        const int u  = tid + it * 256;
        const int r2 = u >> 3;
        const int sg = (u & 7) ^ (r2 & 7);
        dstA[it] = u * 8;
        srcA[it] = (size_t)r2 * 1024 + sg * 8;
    }
    #pragma unroll
    for (int it = 0; it < 2; ++it) {
        const int u  = tid + it * 256;
        const int r2 = u >> 3;
        const int sg = (u & 7) ^ (r2 & 7);
        dstB[it] = u * 8;
        srcB[it] = (size_t)r2 * 1024 + sg * 8;
    }

    f32x4 acc[4][2];
    #pragma unroll
    for (int i = 0; i < 4; ++i)
        #pragma unroll
        for (int j = 0; j < 2; ++j)
            acc[i][j] = (f32x4){0.f, 0.f, 0.f, 0.f};

    #pragma unroll
    for (int it = 0; it < 4; ++it)
        gload_lds16(aBase + srcA[it], &As[0][dstA[it]]);
    #pragma unroll
    for (int it = 0; it < 2; ++it)
        gload_lds16(bBase + srcB[it], &Bs[0][dstB[it]]);

    for (int kt = 0; kt < 16; ++kt) {
        const int cur = kt & 1;
        __syncthreads();

        if (kt < 15) {
            const int k0n = (kt + 1) * 64;
            #pragma unroll
            for (int it = 0; it < 4; ++it)
                gload_lds16(aBase + srcA[it] + k0n, &As[cur ^ 1][dstA[it]]);
            #pragma unroll
            for (int it = 0; it < 2; ++it)
                gload_lds16(bBase + srcB[it] + k0n, &Bs[cur ^ 1][dstB[it]]);
        }

        #pragma unroll
        for (int dc = 0; dc < 2; ++dc) {
            const int sw = ((dc * 4 + g) ^ (lc & 7)) << 3;
            bf16x8 af[4], bfr[2];
            #pragma unroll
            for (int i = 0; i < 4; ++i)
                af[i] = *(const bf16x8*)&As[cur][(wm * 64 + i * 16 + lc) * 64 + sw];
            #pragma unroll
            for (int j = 0; j < 2; ++j)
                bfr[j] = *(const bf16x8*)&Bs[cur][(wn * 32 + j * 16 + lc) * 64 + sw];

            #pragma unroll
            for (int i = 0; i < 4; ++i)
                #pragma unroll
                for (int j = 0; j < 2; ++j)
                    acc[i][j] = __builtin_amdgcn_mfma_f32_16x16x32_bf16(af[i], bfr[j], acc[i][j], 0, 0, 0);
        }
    }

    #pragma unroll
    for (int i = 0; i < 4; ++i) {
        const int mrow = m0 + wm * 64 + i * 16 + g * 4;
        #pragma unroll
        for (int j = 0; j < 2; ++j) {
            const int nc = n0 + wn * 32 + j * 16 + lc;
            #pragma unroll
            for (int r = 0; r < 4; ++r)
                cf[(size_t)(mrow + r) * 1024 + nc] = acc[i][j][r];
        }
    }
}

// ---------------------------------------------------------------------------
// Flash attention v5: KV-SPLIT load balancing. Fixed-shift softmax
// (p = exp(s), no running max) makes otacc/lsum PURE SUMS over jt -> the KV
// loop has no sequential dependency and can be split across blocks, merged
// by addition. This breaks the qt=31 straggler (32 iters) that pinned the
// makespan of every whole-tile schedule (R1/R3/R4: occupancy 10-12%).
// Grid (48 slots x 16 bh), 256 thr, interior identical to R3:
//  slot x in [0,16):  tile qt=31-x,     KV chunk [0, h-1], h=ceil((qt+1)/2)
//  slot x in [16,32): tile qt=47-x,     KV chunk [h, qt]   (has the diag)
//  slot x in [32,48): tile qt=47-x<=15, whole [0, qt]      (sole owner)
// Max chunk 17 iters (vs 32). Split tiles: both halves write f32 merged
// partials; arrival order via device-scope atomic counter (tctr in d_out,
// zeroed by prep): first writes partial to scratch (opart=xb 8MB exact,
// lpart=wqkvT, both dead after gemm_qkv), fences, signals (+1 again);
// second (polls only on near-tie; partner is resident -> no deadlock)
// reads, adds, normalizes, writes ob. Extra HBM ~16MB ~ 2.5 us.
// ---------------------------------------------------------------------------
__global__ __launch_bounds__(256) void flash_attn(const unsigned short* __restrict__ qb,
                                                  const unsigned short* __restrict__ kb,
                                                  const unsigned short* __restrict__ vt,
                                                  unsigned short* __restrict__ o,
                                                  float* __restrict__ opart,
                                                  float* __restrict__ lpart,
                                                  int* __restrict__ tctr)
{
    __shared__ __align__(16) unsigned short smem[2 * 64 * 128 + 2 * 128 * 64 + 128];
    __shared__ int oldLds;
    unsigned short* KsB = smem;
    unsigned short* VsB = smem + 2 * 64 * 128;
    float* lscr = (float*)(smem + 2 * 64 * 128 + 2 * 128 * 64);
    float* scr  = (float*)smem;                    // epilogue scratch [64][129] f32

    const int tid  = threadIdx.x;
    const int lane = tid & 63;
    const int w    = tid >> 6;
    const int wj   = w >> 1;            // j-half
    const int wq2  = w & 1;             // q-half
    const int qcol = lane & 31;
    const int hi   = lane >> 5;         // half-wave

    const int x  = blockIdx.x;          // slot 0..47 (big chunks first)
    const int bh = blockIdx.y;          // 0..15
    int qt, jlo, jhi;
    bool split;
    if (x < 32) {
        qt = 31 - (x & 15);
        const int hsp = (qt + 2) >> 1;   // ceil((qt+1)/2)
        split = true;
        if (x < 16) { jlo = 0;   jhi = hsp - 1; }
        else        { jlo = hsp; jhi = qt; }
    } else {
        qt = 47 - x; jlo = 0; jhi = qt; split = false;
    }
    const int q0 = qt * 64;
    const int h  = bh & (H_ - 1);
    const int b  = bh >> 3;

    const size_t bhbase  = (size_t)b * T_ * HD + (size_t)h * 128;   // q,k,o
    const size_t bhvbase = (size_t)bh * 128 * T_;                   // vt

    int mI[4];
    size_t srcKoff[4], srcVoff[4];
    #pragma unroll
    for (int it = 0; it < 4; ++it) {
        const int m = (w * 4 + it) * 64 + lane;
        mI[it] = m;
        const int jK = m >> 4, cK = (m & 15) ^ (jK & 15);
        srcKoff[it] = (size_t)jK * 1024 + cK * 8;
        const int dV = m >> 3, cV = (m & 7) ^ (dV & 7);
        srcVoff[it] = (size_t)dV * T_ + cV * 8;
    }
    const unsigned short* kgb = kb + bhbase;
    const unsigned short* vgb = vt + bhvbase;

    // Q as B-operand frags
    bf16x8 qf[8];
    {
        const unsigned short* qp = qb + bhbase + (size_t)(q0 + wq2 * 32 + qcol) * 1024 + hi * 8;
        #pragma unroll
        for (int ks = 0; ks < 8; ++ks)
            qf[ks] = *(const bf16x8*)(qp + ks * 16);
    }

    float lsum = 0.f;
    f32x16 otacc[4];
    #pragma unroll
    for (int dch = 0; dch < 4; ++dch)
        #pragma unroll
        for (int r = 0; r < 16; ++r) otacc[dch][r] = 0.f;

    // prologue: stage jt=jlo into buffer 0
    {
        const size_t j00 = (size_t)jlo * 64;
        #pragma unroll
        for (int it = 0; it < 4; ++it) {
            gload_lds16(kgb + j00 * 1024 + srcKoff[it], &KsB[mI[it] * 8]);
            gload_lds16(vgb + j00 + srcVoff[it], &VsB[mI[it] * 8]);
        }
    }

    for (int jt = jlo; jt <= jhi; ++jt) {
        const int cur = (jt - jlo) & 1;
        unsigned short* Ks = KsB + cur * (64 * 128);
        unsigned short* Vs = VsB + cur * (128 * 64);
        __syncthreads();

        if (jt < jhi) {
            const size_t j0n = (size_t)(jt + 1) * 64;
            unsigned short* Kn = KsB + (cur ^ 1) * (64 * 128);
            unsigned short* Vn = VsB + (cur ^ 1) * (128 * 64);
            #pragma unroll
            for (int it = 0; it < 4; ++it) {
                gload_lds16(kgb + j0n * 1024 + srcKoff[it], &Kn[mI[it] * 8]);
                gload_lds16(vgb + j0n + srcVoff[it], &Vn[mI[it] * 8]);
            }
        }

        const bool dead = (jt == qt) && (wj > wq2);
        if (!dead) {
            const int jrow = wj * 32 + qcol;

            // batch-issue operand reads (8 K-frags + 8 V-frags)
            bf16x8 kf[8], vf[8];
            #pragma unroll
            for (int ks = 0; ks < 8; ++ks) {
                const int c = ks * 2 + hi;
                kf[ks] = *(const bf16x8*)&Ks[(jrow * 16 + (c ^ (lane & 15))) * 8];
            }
            #pragma unroll
            for (int ks2 = 0; ks2 < 2; ++ks2)
                #pragma unroll
                for (int dch = 0; dch < 4; ++dch) {
                    const int c = wj * 4 + ks2 * 2 + hi;
                    const int drow = dch * 32 + qcol;
                    vf[ks2 * 4 + dch] = *(const bf16x8*)&Vs[(drow * 8 + (c ^ (lane & 7))) * 8];
                }

            // ---- S^T = K Q^T : two parallel accumulation chains ----
            f32x16 sacc0, sacc1;
            #pragma unroll
            for (int r = 0; r < 16; ++r) { sacc0[r] = 0.f; sacc1[r] = 0.f; }
            __builtin_amdgcn_s_setprio(1);
            #pragma unroll
            for (int ks = 0; ks < 8; ks += 2) {
                sacc0 = __builtin_amdgcn_mfma_f32_32x32x16_bf16(kf[ks], qf[ks], sacc0, 0, 0, 0);
                sacc1 = __builtin_amdgcn_mfma_f32_32x32x16_bf16(kf[ks + 1], qf[ks + 1], sacc1, 0, 0, 0);
            }
            __builtin_amdgcn_s_setprio(0);
            f32x16 sacc = sacc0 + sacc1;

            if (jt == qt && wj == wq2) {
                #pragma unroll
                for (int r = 0; r < 16; ++r) {
                    const int jl = (r & 3) + 8 * (r >> 2) + 4 * hi;
                    if (qcol < jl) sacc[r] = -1e30f;
                }
            }

            unsigned int dw[8];
            #pragma unroll
            for (int m2 = 0; m2 < 8; ++m2) {
                const float p0 = __expf(sacc[2 * m2]);
                const float p1 = __expf(sacc[2 * m2 + 1]);
                lsum += p0 + p1;
                dw[m2] = pk2bf(p0, p1);
            }

            // P^T C-layout -> PV B-frags via permlane32_swap
            __builtin_amdgcn_s_setprio(1);
            #pragma unroll
            for (int ks2 = 0; ks2 < 2; ++ks2) {
                const uint32x2 s02 = __builtin_amdgcn_permlane32_swap(
                    dw[4 * ks2 + 0], dw[4 * ks2 + 2], 0, 0);
                const uint32x2 s13 = __builtin_amdgcn_permlane32_swap(
                    dw[4 * ks2 + 1], dw[4 * ks2 + 3], 0, 0);
                union { unsigned int u2[4]; bf16x8 v; } pf;
                pf.u2[0] = s02[0];
                pf.u2[1] = s13[0];
                pf.u2[2] = s02[1];
                pf.u2[3] = s13[1];
                #pragma unroll
                for (int dch = 0; dch < 4; ++dch)
                    otacc[dch] = __builtin_amdgcn_mfma_f32_32x32x16_bf16(vf[ks2 * 4 + dch], pf.v, otacc[dch], 0, 0, 0);
            }
            __builtin_amdgcn_s_setprio(0);
        }
    }

    // epilogue: merge wj pairs via LDS
    lsum += __shfl_xor(lsum, 32);
    __syncthreads();

    if (wj == 1) {
        float* s0 = scr + (size_t)(wq2 * 32 + qcol) * 129;
        #pragma unroll
        for (int dch = 0; dch < 4; ++dch)
            #pragma unroll
            for (int r = 0; r < 16; ++r)
                s0[dch * 32 + (r & 3) + 8 * (r >> 2) + 4 * hi] = otacc[dch][r];
        if (hi == 0) lscr[wq2 * 32 + qcol] = lsum;
    }
    __syncthreads();

    const int row = wq2 * 32 + qcol;                 // wj==0: owned q-row
    const float* s0 = scr + (size_t)row * 129;
    float l = 0.f;
    if (wj == 0) l = lsum + lscr[row];

    if (!split) {
        if (wj == 0) {
            const float inv = 1.0f / l;
            unsigned short* op = o + bhbase + (size_t)(q0 + row) * 1024;
            #pragma unroll
            for (int dch = 0; dch < 4; ++dch) {
                #pragma unroll
                for (int k4 = 0; k4 < 4; ++k4) {
                    const int d0 = dch * 32 + 8 * k4 + 4 * hi;
                    const float f0 = (otacc[dch][4 * k4 + 0] + s0[d0 + 0]) * inv;
                    const float f1 = (otacc[dch][4 * k4 + 1] + s0[d0 + 1]) * inv;
                    const float f2 = (otacc[dch][4 * k4 + 2] + s0[d0 + 2]) * inv;
                    const float f3 = (otacc[dch][4 * k4 + 3] + s0[d0 + 3]) * inv;
                    uint2 val;
                    val.x = pk2bf(f0, f1);
                    val.y = pk2bf(f2, f3);
                    *(uint2*)(op + d0) = val;
                }
            }
        }
    } else {
        const int tidx = bh * 16 + (qt - 16);        // 0..255
        float* po = opart + (size_t)tidx * (64 * 128);

        if (tid == 0) oldLds = atomicAdd(&tctr[tidx], 1);
        __syncthreads();

        if (oldLds == 0) {
            // first finisher: publish merged partial, fence, signal
            if (wj == 0) {
                float* pr = po + row * 128;
                #pragma unroll
                for (int dch = 0; dch < 4; ++dch)
                    #pragma unroll
                    for (int k4 = 0; k4 < 4; ++k4) {
                        const int d0 = dch * 32 + 8 * k4 + 4 * hi;
                        float4 v;
                        v.x = otacc[dch][4 * k4 + 0] + s0[d0 + 0];
                        v.y = otacc[dch][4 * k4 + 1] + s0[d0 + 1];
                        v.z = otacc[dch][4 * k4 + 2] + s0[d0 + 2];
                        v.w = otacc[dch][4 * k4 + 3] + s0[d0 + 3];
                        *(float4*)(pr + d0) = v;
                    }
                if (hi == 0) lpart[tidx * 64 + row] = l;
            }
            __threadfence();
            __syncthreads();                          // all writes fenced
            if (tid == 0) atomicAdd(&tctr[tidx], 1);  // "data ready" (-> >=2)
        } else {
            // second finisher: wait for partner's ready signal, then merge.
            // Counter states at my arrival-add: 1 (partner arrived, maybe
            // still writing) or 2 (ready). After my add: poll until >= 3.
            if (tid == 0) {
                while (atomicAdd(&tctr[tidx], 0) < 3)
                    __builtin_amdgcn_s_sleep(16);
            }
            __syncthreads();
            __threadfence();
            if (wj == 0) {
                const float inv = 1.0f / (l + lpart[tidx * 64 + row]);
                const float* pr = po + row * 128;
                unsigned short* op = o + bhbase + (size_t)(q0 + row) * 1024;
                #pragma unroll
                for (int dch = 0; dch < 4; ++dch) {
                    #pragma unroll
                    for (int k4 = 0; k4 < 4; ++k4) {
                        const int d0 = dch * 32 + 8 * k4 + 4 * hi;
                        const float4 pv = *(const float4*)(pr + d0);
                        const float f0 = (otacc[dch][4 * k4 + 0] + s0[d0 + 0] + pv.x) * inv;
                        const float f1 = (otacc[dch][4 * k4 + 1] + s0[d0 + 1] + pv.y) * inv;
                        const float f2 = (otacc[dch][4 * k4 + 2] + s0[d0 + 2] + pv.z) * inv;
                        const float f3 = (otacc[dch][4 * k4 + 3] + s0[d0 + 3] + pv.w) * inv;
                        uint2 val;
                        val.x = pk2bf(f0, f1);
                        val.y = pk2bf(f2, f3);
                        *(uint2*)(op + d0) = val;
                    }
                }
            }
        }
    }
}

// ---------------------------------------------------------------------------
extern "C" void kernel_launch(void* const* d_in, const int* in_sizes, int n_in,
                              void* d_out, int out_size, void* d_ws, size_t ws_size,
                              hipStream_t stream)
{
    const float* x  = (const float*)d_in[0];
    const float* wq = (const float*)d_in[1];
    const float* wk = (const float*)d_in[2];
    const float* wv = (const float*)d_in[3];
    const float* wo = (const float*)d_in[4];
    float* out = (float*)d_out;

    const size_t SZ = (size_t)NROW * HD;               // 4M elements
    unsigned short* qb    = (unsigned short*)d_ws;     // 8 MB
    unsigned short* kb    = qb + SZ;                   // 8 MB
    unsigned short* vt    = kb + SZ;                   // 8 MB [(b,h),d,t]
    unsigned short* ob    = vt + SZ;                   // 8 MB
    unsigned short* xb    = ob + SZ;                   // 8 MB
    unsigned short* wqkvT = xb + SZ;                   // 6 MB [3072][1024]
    unsigned short* woT   = wqkvT + 3 * 1024 * 1024;   // 2 MB

    float* opart = (float*)xb;      // 8 MB scratch (dead after gemm_qkv)
    float* lpart = (float*)wqkvT;   // 64 KB scratch (dead after gemm_qkv)
    int*   tctr  = (int*)out;       // 256 counters (d_out, rewritten by gemm_out)

    // prologue: x cast + 4 weight transposes + counter zero, one launch
    prep<<<dim3(32, 32, 5), 256, 0, stream>>>(x, wq, wk, wv, wo, xb, wqkvT, woT, tctr);

    // fused QKV projection (+ RMSNorm/RoPE on q,k; V written transposed)
    gemm_qkv<<<dim3(24, 32), 256, 0, stream>>>(xb, wqkvT, qb, kb, vt);

    // KV-split balanced flash attention (48 slots x 16 bh)
    flash_attn<<<dim3(48, 16), 256, 0, stream>>>(qb, kb, vt, ob, opart, lpart, tctr);

    // output projection, 128x64 tiles -> 512 blocks
    gemm_out<<<dim3(16, 32), 256, 0, stream>>>(ob, woT, out);
}

// Round 6
// 187.564 us; speedup vs baseline: 1.4843x; 1.4843x over previous
//
#include <hip/hip_runtime.h>
#include <hip/hip_bf16.h>
#include <math.h>

// Problem constants: B=2, T=2048, M=1024, H=8, D=128
#define B_  2
#define T_  2048
#define M_  1024
#define H_  8
#define D_  128
#define NROW (B_ * T_)          // 4096
#define HD  (H_ * D_)           // 1024

#define NORM_EPS 1e-6f
#define QK_MULT  0.08838834764831845f   // sqrt(1/128)
#define LN_BASE_64 0.14391156510f       // ln(10000)/64

typedef short bf16x8  __attribute__((ext_vector_type(8)));    // 8 bf16 = 4 VGPRs
typedef float f32x4   __attribute__((ext_vector_type(4)));
typedef float f32x16  __attribute__((ext_vector_type(16)));
typedef unsigned int uint32x2 __attribute__((ext_vector_type(2)));

static __device__ __forceinline__ unsigned short f2bf(float f) {
    union { __hip_bfloat16 h; unsigned short u; } cv;
    cv.h = __float2bfloat16(f);
    return cv.u;
}
static __device__ __forceinline__ unsigned int pk2bf(float a, float b) {
    return ((unsigned int)f2bf(b) << 16) | f2bf(a);
}

// async global->LDS, 16 bytes per lane. LDS dest = wave-uniform base + lane*16.
static __device__ __forceinline__ void gload_lds16(const unsigned short* g,
                                                   unsigned short* l) {
    __builtin_amdgcn_global_load_lds(
        (const __attribute__((address_space(1))) void*)g,
        (__attribute__((address_space(3))) void*)l, 16, 0, 0);
}

// ---------------------------------------------------------------------------
// prep: z<4 -> transpose+cast weight z (out[n][k]=bf16(in[k][n]));
//       z==4 -> linear cast of x to bf16.
// ---------------------------------------------------------------------------
__global__ __launch_bounds__(256) void prep(const float* __restrict__ x,
                                            const float* __restrict__ w0,
                                            const float* __restrict__ w1,
                                            const float* __restrict__ w2,
                                            const float* __restrict__ w3,
                                            unsigned short* __restrict__ xb,
                                            unsigned short* __restrict__ wqkvT,
                                            unsigned short* __restrict__ woT)
{
    __shared__ float t[32][33];
    const int z = blockIdx.z;
    if (z == 4) {
        const size_t base = ((size_t)blockIdx.y * 32 + blockIdx.x) * 4096;
        #pragma unroll
        for (int it = 0; it < 4; ++it) {
            const size_t i = base + it * 1024 + threadIdx.x * 4;
            const float4 v = *(const float4*)(x + i);
            ushort4 o;
            o.x = f2bf(v.x); o.y = f2bf(v.y); o.z = f2bf(v.z); o.w = f2bf(v.w);
            *(ushort4*)(xb + i) = o;
        }
        return;
    }
    const float* in = z == 0 ? w0 : (z == 1 ? w1 : (z == 2 ? w2 : w3));
    unsigned short* out = z < 3 ? (wqkvT + (size_t)z * 1024 * 1024) : woT;

    const int tx = threadIdx.x & 31;
    const int ty = threadIdx.x >> 5;
    const int n0 = blockIdx.x * 32;
    const int k0 = blockIdx.y * 32;
    #pragma unroll
    for (int r = 0; r < 4; ++r)
        t[ty + r * 8][tx] = in[(size_t)(k0 + ty + r * 8) * 1024 + n0 + tx];
    __syncthreads();
    #pragma unroll
    for (int r = 0; r < 4; ++r)
        out[(size_t)(n0 + ty + r * 8) * 1024 + k0 + tx] = f2bf(t[tx][ty + r * 8]);
}

// ---------------------------------------------------------------------------
// QKV GEMM: C = A[4096x1024] * Bt[3072x1024]^T. 128x128 tile, BK=32,
// async double-buffered global_load_lds staging, 3 blocks/CU. V epilogue
// transposes via LDS so vt is written in contiguous 256-B rows (kills the
// ~24 MB write-allocate overfetch of the old 8-B/4-KB-stride scatter).
// ---------------------------------------------------------------------------
__global__ __launch_bounds__(256) void gemm_qkv(const unsigned short* __restrict__ A,
                                                const unsigned short* __restrict__ Bt,
                                                unsigned short* __restrict__ oq,
                                                unsigned short* __restrict__ ok,
                                                unsigned short* __restrict__ vt)
{
    __shared__ __align__(16) unsigned short smem[17408];   // 34 KB
    #define AsQ(buf) (smem + (buf) * 4096)
    #define BsQ(buf) (smem + 8192 + (buf) * 4096)

    const int tid  = threadIdx.x;
    const int lane = tid & 63;
    const int w    = tid >> 6;          // wave = row band (32 rows)
    const int g    = lane >> 4;
    const int lc   = lane & 15;

    const int m0 = blockIdx.y * 128;
    const int n0 = blockIdx.x * 128;

    const unsigned short* aBase = A  + (size_t)m0 * 1024;
    const unsigned short* bBase = Bt + (size_t)n0 * 1024;

    int dstOff[2];
    size_t srcOff[2];
    #pragma unroll
    for (int it = 0; it < 2; ++it) {
        const int u  = tid + it * 256;      // 0..511
        const int r2 = u >> 2;              // tile row
        const int sg = (u & 3) ^ (r2 & 3);  // src segment (XOR swizzle)
        dstOff[it] = u * 8;
        srcOff[it] = (size_t)r2 * 1024 + sg * 8;
    }

    f32x4 acc[2][8];
    #pragma unroll
    for (int i = 0; i < 2; ++i)
        #pragma unroll
        for (int j = 0; j < 8; ++j)
            acc[i][j] = (f32x4){0.f, 0.f, 0.f, 0.f};

    #pragma unroll
    for (int it = 0; it < 2; ++it) {
        gload_lds16(aBase + srcOff[it], AsQ(0) + dstOff[it]);
        gload_lds16(bBase + srcOff[it], BsQ(0) + dstOff[it]);
    }

    for (int kt = 0; kt < 32; ++kt) {
        const int cur = kt & 1;
        __syncthreads();                      // tile kt ready; buf^1 free

        if (kt < 31) {                        // async-prefetch next K-tile
            const int k0n = (kt + 1) * 32;
            #pragma unroll
            for (int it = 0; it < 2; ++it) {
                gload_lds16(aBase + srcOff[it] + k0n, AsQ(cur ^ 1) + dstOff[it]);
                gload_lds16(bBase + srcOff[it] + k0n, BsQ(cur ^ 1) + dstOff[it]);
            }
        }

        const int sw = (g ^ (lc & 3)) << 3;
        bf16x8 af[2], bfr[8];
        #pragma unroll
        for (int i = 0; i < 2; ++i)
            af[i] = *(const bf16x8*)&AsQ(cur)[(w * 32 + i * 16 + lc) * 32 + sw];
        #pragma unroll
        for (int j = 0; j < 8; ++j)
            bfr[j] = *(const bf16x8*)&BsQ(cur)[(j * 16 + lc) * 32 + sw];

        #pragma unroll
        for (int i = 0; i < 2; ++i)
            #pragma unroll
            for (int j = 0; j < 8; ++j)
                acc[i][j] = __builtin_amdgcn_mfma_f32_16x16x32_bf16(af[i], bfr[j], acc[i][j], 0, 0, 0);
    }

    const int which = n0 >> 10;
    const int ncol0 = n0 & 1023;            // head-aligned (tile = one head)
    if (which < 2) {
        // ---- fused RMSNorm + RoPE + sqrt(qk_scale) for q / k ----
        unsigned short* outp = which == 0 ? oq : ok;
        float freq[4];
        #pragma unroll
        for (int j = 0; j < 4; ++j)
            freq[j] = __expf(-(float)(j * 16 + lc) * LN_BASE_64);

        #pragma unroll
        for (int i = 0; i < 2; ++i)
            #pragma unroll
            for (int r = 0; r < 4; ++r) {
                float s = 0.f;
                #pragma unroll
                for (int j = 0; j < 8; ++j) s += acc[i][j][r] * acc[i][j][r];
                #pragma unroll
                for (int off = 1; off < 16; off <<= 1) s += __shfl_xor(s, off);
                const float rms = rsqrtf(s * (1.0f / 128.0f) + NORM_EPS) * QK_MULT;

                const int trow = m0 + w * 32 + i * 16 + g * 4 + r;
                const float tpos = (float)(trow & (T_ - 1));
                unsigned short* op = outp + (size_t)trow * 1024 + ncol0;
                #pragma unroll
                for (int j = 0; j < 4; ++j) {
                    float sn, cs;
                    __sincosf(tpos * freq[j], &sn, &cs);
                    const float e = acc[i][j][r] * rms;       // even half
                    const float o = acc[i][j + 4][r] * rms;   // odd half (+64)
                    op[j * 16 + lc]      = f2bf(e * cs - o * sn);
                    op[j * 16 + lc + 64] = f2bf(e * sn + o * cs);
                }
            }
    } else {
        // V: transpose in LDS, then dump contiguous 256-B rows ->
        // vt[(b*8+h)*128 + d][t]. Full-line writes, no write-allocate RMW.
        const int b2 = m0 >> 11;
        const int hh = ncol0 >> 7;
        const int PAD = 136;                 // 272 B rows: 16-B aligned, odd*16
        __syncthreads();                     // staging reads done; reuse smem
        #pragma unroll
        for (int i = 0; i < 2; ++i) {
            const int t0 = w * 32 + i * 16 + g * 4;
            #pragma unroll
            for (int j = 0; j < 8; ++j) {
                uint2 val;
                val.x = pk2bf(acc[i][j][0], acc[i][j][1]);
                val.y = pk2bf(acc[i][j][2], acc[i][j][3]);
                *(uint2*)&smem[(j * 16 + lc) * PAD + t0] = val;
            }
        }
        __syncthreads();
        const int row  = tid >> 1;           // d (0..127)
        const int half = tid & 1;            // t half (64 shorts)
        const unsigned short* src = &smem[row * PAD + half * 64];
        unsigned short* dst = vt + ((size_t)(b2 * 8 + hh) * 128 + row) * T_
                                 + (m0 & 2047) + half * 64;
        #pragma unroll
        for (int it2 = 0; it2 < 8; ++it2)
            *(uint4*)(dst + it2 * 8) = *(const uint4*)(src + it2 * 8);
    }
    #undef AsQ
    #undef BsQ
}

// ---------------------------------------------------------------------------
// Output projection: C[4096x1024] fp32 = A * Bt^T. 128x64 tile (512 blocks,
// 3/CU, all resident), BK=64, async double-buffered staging + XOR swizzle.
// 2x2 waves of 64x32.
// ---------------------------------------------------------------------------
__global__ __launch_bounds__(256) void gemm_out(const unsigned short* __restrict__ A,
                                                const unsigned short* __restrict__ Bt,
                                                float* __restrict__ cf)
{
    __shared__ unsigned short As[2][128 * 64];   // 2 x 16 KB
    __shared__ unsigned short Bs[2][64 * 64];    // 2 x 8 KB  (48 KB total)

    const int tid  = threadIdx.x;
    const int lane = tid & 63;
    const int w    = tid >> 6;
    const int g    = lane >> 4;
    const int lc   = lane & 15;
    const int wm   = w >> 1;
    const int wn   = w & 1;

    const int m0 = blockIdx.y * 128;
    const int n0 = blockIdx.x * 64;

    const unsigned short* aBase = A  + (size_t)m0 * 1024;
    const unsigned short* bBase = Bt + (size_t)n0 * 1024;

    int dstA[4], dstB[2];
    size_t srcA[4], srcB[2];
    #pragma unroll
    for (int it = 0; it < 4; ++it) {
        const int u  = tid + it * 256;
        const int r2 = u >> 3;
        const int sg = (u & 7) ^ (r2 & 7);
        dstA[it] = u * 8;
        srcA[it] = (size_t)r2 * 1024 + sg * 8;
    }
    #pragma unroll
    for (int it = 0; it < 2; ++it) {
        const int u  = tid + it * 256;
        const int r2 = u >> 3;
        const int sg = (u & 7) ^ (r2 & 7);
        dstB[it] = u * 8;
        srcB[it] = (size_t)r2 * 1024 + sg * 8;
    }

    f32x4 acc[4][2];
    #pragma unroll
    for (int i = 0; i < 4; ++i)
        #pragma unroll
        for (int j = 0; j < 2; ++j)
            acc[i][j] = (f32x4){0.f, 0.f, 0.f, 0.f};

    #pragma unroll
    for (int it = 0; it < 4; ++it)
        gload_lds16(aBase + srcA[it], &As[0][dstA[it]]);
    #pragma unroll
    for (int it = 0; it < 2; ++it)
        gload_lds16(bBase + srcB[it], &Bs[0][dstB[it]]);

    for (int kt = 0; kt < 16; ++kt) {
        const int cur = kt & 1;
        __syncthreads();

        if (kt < 15) {
            const int k0n = (kt + 1) * 64;
            #pragma unroll
            for (int it = 0; it < 4; ++it)
                gload_lds16(aBase + srcA[it] + k0n, &As[cur ^ 1][dstA[it]]);
            #pragma unroll
            for (int it = 0; it < 2; ++it)
                gload_lds16(bBase + srcB[it] + k0n, &Bs[cur ^ 1][dstB[it]]);
        }

        #pragma unroll
        for (int dc = 0; dc < 2; ++dc) {
            const int sw = ((dc * 4 + g) ^ (lc & 7)) << 3;
            bf16x8 af[4], bfr[2];
            #pragma unroll
            for (int i = 0; i < 4; ++i)
                af[i] = *(const bf16x8*)&As[cur][(wm * 64 + i * 16 + lc) * 64 + sw];
            #pragma unroll
            for (int j = 0; j < 2; ++j)
                bfr[j] = *(const bf16x8*)&Bs[cur][(wn * 32 + j * 16 + lc) * 64 + sw];

            #pragma unroll
            for (int i = 0; i < 4; ++i)
                #pragma unroll
                for (int j = 0; j < 2; ++j)
                    acc[i][j] = __builtin_amdgcn_mfma_f32_16x16x32_bf16(af[i], bfr[j], acc[i][j], 0, 0, 0);
        }
    }

    #pragma unroll
    for (int i = 0; i < 4; ++i) {
        const int mrow = m0 + wm * 64 + i * 16 + g * 4;
        #pragma unroll
        for (int j = 0; j < 2; ++j) {
            const int nc = n0 + wn * 32 + j * 16 + lc;
            #pragma unroll
            for (int r = 0; r < 4; ++r)
                cf[(size_t)(mrow + r) * 1024 + nc] = acc[i][j][r];
        }
    }
}

// ---------------------------------------------------------------------------
// Flash attention v6: deep-pipelined staging + QBLK=128.
// R5 post-mortem: the per-iter cost was the __syncthreads vmcnt(0) drain --
// the DMA issued ~600cy earlier must complete, exposing the full ~2000cy
// L2/HBM round-trip EVERY iteration (1 wave/SIMD of TLP, nothing hides it).
// Fix (T3/T4): 3-buffer rotation, stage jt+2 issued right after the
// barrier, and the pre-barrier wait is a COUNTED vmcnt(4) -- it only waits
// for stage jt (issued one full iteration earlier), never the in-flight
// jt+1/jt+2. Buffer-reuse safety: stage(jt+2) overwrites buf (jt-1)%3,
// whose readers all passed the barrier at top of jt.
// QBLK=128, 512 thr / 8 waves = (wj in {0,1}) x (qg in {0..3}); wave
// interior identical to v3 (qg replaces wq2). Halves staged bytes per unit
// of compute. Grid 16x16 = 256 blocks, 1/CU, LDS 97 KB.
// Causal masking: e = qg - 2*(jt - 2*qb) - wj; e<0 dead, e==0 diag mask
// (qcol < jl), e>0 full tile. Verified for all 8 wave roles.
// Fixed-shift softmax (p = exp(s), s in [-1,1]); permlane32_swap P
// redistribution; setprio around MFMA clusters.
// ---------------------------------------------------------------------------
__global__ __launch_bounds__(512) void flash_attn(const unsigned short* __restrict__ qb,
                                                  const unsigned short* __restrict__ kb,
                                                  const unsigned short* __restrict__ vt,
                                                  unsigned short* __restrict__ o)
{
    // 3 x (K 16KB + V 16KB) = 96 KB staging + 512 B lscr; epilogue scratch
    // [128][129] f32 (66 KB) reuses the staging area after the last barrier.
    __shared__ __align__(16) unsigned short smem[6 * 8192 + 256];
    unsigned short* K3 = smem;                   // 3 x [64*128]
    unsigned short* V3 = smem + 3 * 8192;        // 3 x [128*64]
    float* lscr = (float*)(smem + 6 * 8192);     // 128 f32
    float* scr  = (float*)smem;                  // epilogue [128][129] f32

    const int tid  = threadIdx.x;
    const int lane = tid & 63;
    const int w    = tid >> 6;          // 0..7
    const int qg   = w & 3;             // q 32-row group within 128-row tile
    const int wj   = w >> 2;            // j-half of the 64-wide KV tile
    const int qcol = lane & 31;
    const int hi   = lane >> 5;         // half-wave

    const int qbk = blockIdx.x;         // q-tile of 128 rows (0..15)
    const int bh  = blockIdx.y;         // 0..15
    const int jmax = 2 * qbk + 1;       // last KV 64-tile
    const int q0  = qbk * 128;
    const int h   = bh & (H_ - 1);
    const int b   = bh >> 3;

    const size_t bhbase  = (size_t)b * T_ * HD + (size_t)h * 128;   // q,k,o
    const size_t bhvbase = (size_t)bh * 128 * T_;                   // vt

    // staging offsets: 2 K chunks + 2 V chunks per thread (512 thr)
    int mK[2], mV[2];
    size_t srcK[2], srcV[2];
    #pragma unroll
    for (int it = 0; it < 2; ++it) {
        const int m = tid + it * 512;            // 0..1023
        mK[it] = m;
        const int jK = m >> 4, cK = (m & 15) ^ (jK & 15);
        srcK[it] = (size_t)jK * 1024 + cK * 8;
        mV[it] = m;
        const int dV = m >> 3, cV = (m & 7) ^ (dV & 7);
        srcV[it] = (size_t)dV * T_ + cV * 8;
    }
    const unsigned short* kgb = kb + bhbase;
    const unsigned short* vgb = vt + bhvbase;

#define STAGE(jt_, b_) {                                                     \
        const size_t jo = (size_t)(jt_) * 64;                                \
        unsigned short* Kd = K3 + (b_) * 8192;                               \
        unsigned short* Vd = V3 + (b_) * 8192;                               \
        _Pragma("unroll")                                                    \
        for (int it = 0; it < 2; ++it)                                       \
            gload_lds16(kgb + jo * 1024 + srcK[it], &Kd[mK[it] * 8]);        \
        _Pragma("unroll")                                                    \
        for (int it = 0; it < 2; ++it)                                       \
            gload_lds16(vgb + jo + srcV[it], &Vd[mV[it] * 8]);               \
    }

    // Q as B-operand frags (wave's 32 q-rows)
    bf16x8 qf[8];
    {
        const unsigned short* qp = qb + bhbase + (size_t)(q0 + qg * 32 + qcol) * 1024 + hi * 8;
        #pragma unroll
        for (int ks = 0; ks < 8; ++ks)
            qf[ks] = *(const bf16x8*)(qp + ks * 16);
    }

    float lsum = 0.f;
    f32x16 otacc[4];
    #pragma unroll
    for (int dch = 0; dch < 4; ++dch)
        #pragma unroll
        for (int r = 0; r < 16; ++r) otacc[dch][r] = 0.f;

    // prologue: stage tiles 0 and 1 (jmax >= 1 always)
    STAGE(0, 0);
    STAGE(1, 1);

    for (int jt = 0; jt <= jmax; ++jt) {
        // counted wait: only stage jt must be complete; jt+1 (4 loads) may fly
        if (jt < jmax) asm volatile("s_waitcnt vmcnt(4)" ::: "memory");
        else           asm volatile("s_waitcnt vmcnt(0)" ::: "memory");
        __builtin_amdgcn_s_barrier();
        // stage jt+2 into buf (jt+2)%3 == (jt-1)%3: all readers passed barrier
        if (jt + 2 <= jmax) STAGE(jt + 2, (jt + 2) % 3);

        unsigned short* Ks = K3 + (jt % 3) * 8192;
        unsigned short* Vs = V3 + (jt % 3) * 8192;

        const int e = qg - 2 * (jt - 2 * qbk) - wj;
        if (e >= 0) {
            const int jrow = wj * 32 + qcol;

            // batch-issue operand reads (8 K-frags + 8 V-frags)
            bf16x8 kf[8], vf[8];
            #pragma unroll
            for (int ks = 0; ks < 8; ++ks) {
                const int c = ks * 2 + hi;
                kf[ks] = *(const bf16x8*)&Ks[(jrow * 16 + (c ^ (lane & 15))) * 8];
            }
            #pragma unroll
            for (int ks2 = 0; ks2 < 2; ++ks2)
                #pragma unroll
                for (int dch = 0; dch < 4; ++dch) {
                    const int c = wj * 4 + ks2 * 2 + hi;
                    const int drow = dch * 32 + qcol;
                    vf[ks2 * 4 + dch] = *(const bf16x8*)&Vs[(drow * 8 + (c ^ (lane & 7))) * 8];
                }

            // ---- S^T = K Q^T : two parallel accumulation chains ----
            f32x16 sacc0, sacc1;
            #pragma unroll
            for (int r = 0; r < 16; ++r) { sacc0[r] = 0.f; sacc1[r] = 0.f; }
            __builtin_amdgcn_s_setprio(1);
            #pragma unroll
            for (int ks = 0; ks < 8; ks += 2) {
                sacc0 = __builtin_amdgcn_mfma_f32_32x32x16_bf16(kf[ks], qf[ks], sacc0, 0, 0, 0);
                sacc1 = __builtin_amdgcn_mfma_f32_32x32x16_bf16(kf[ks + 1], qf[ks + 1], sacc1, 0, 0, 0);
            }
            __builtin_amdgcn_s_setprio(0);
            f32x16 sacc = sacc0 + sacc1;

            if (e == 0) {                    // diagonal 32x32 square
                #pragma unroll
                for (int r = 0; r < 16; ++r) {
                    const int jl = (r & 3) + 8 * (r >> 2) + 4 * hi;
                    if (qcol < jl) sacc[r] = -1e30f;
                }
            }

            unsigned int dw[8];
            #pragma unroll
            for (int m2 = 0; m2 < 8; ++m2) {
                const float p0 = __expf(sacc[2 * m2]);
                const float p1 = __expf(sacc[2 * m2 + 1]);
                lsum += p0 + p1;
                dw[m2] = pk2bf(p0, p1);
            }

            // P^T C-layout -> PV B-frags via permlane32_swap
            __builtin_amdgcn_s_setprio(1);
            #pragma unroll
            for (int ks2 = 0; ks2 < 2; ++ks2) {
                const uint32x2 s02 = __builtin_amdgcn_permlane32_swap(
                    dw[4 * ks2 + 0], dw[4 * ks2 + 2], 0, 0);
                const uint32x2 s13 = __builtin_amdgcn_permlane32_swap(
                    dw[4 * ks2 + 1], dw[4 * ks2 + 3], 0, 0);
                union { unsigned int u2[4]; bf16x8 v; } pf;
                pf.u2[0] = s02[0];
                pf.u2[1] = s13[0];
                pf.u2[2] = s02[1];
                pf.u2[3] = s13[1];
                #pragma unroll
                for (int dch = 0; dch < 4; ++dch)
                    otacc[dch] = __builtin_amdgcn_mfma_f32_32x32x16_bf16(vf[ks2 * 4 + dch], pf.v, otacc[dch], 0, 0, 0);
            }
            __builtin_amdgcn_s_setprio(0);
        }
    }
#undef STAGE

    // epilogue: merge wj pairs (per qg) via LDS, write O bf16
    lsum += __shfl_xor(lsum, 32);
    __syncthreads();                         // all compute + DMA done

    const int row = qg * 32 + qcol;          // 0..127
    if (wj == 1) {
        float* s0 = scr + (size_t)row * 129;
        #pragma unroll
        for (int dch = 0; dch < 4; ++dch)
            #pragma unroll
            for (int r = 0; r < 16; ++r)
                s0[dch * 32 + (r & 3) + 8 * (r >> 2) + 4 * hi] = otacc[dch][r];
        if (hi == 0) lscr[row] = lsum;
    }
    __syncthreads();
    if (wj == 0) {
        const float l = lsum + lscr[row];
        const float inv = 1.0f / l;
        const float* s0 = scr + (size_t)row * 129;
        unsigned short* op = o + bhbase + (size_t)(q0 + row) * 1024;
        #pragma unroll
        for (int dch = 0; dch < 4; ++dch) {
            #pragma unroll
            for (int k4 = 0; k4 < 4; ++k4) {
                const int d0 = dch * 32 + 8 * k4 + 4 * hi;
                const float f0 = (otacc[dch][4 * k4 + 0] + s0[d0 + 0]) * inv;
                const float f1 = (otacc[dch][4 * k4 + 1] + s0[d0 + 1]) * inv;
                const float f2 = (otacc[dch][4 * k4 + 2] + s0[d0 + 2]) * inv;
                const float f3 = (otacc[dch][4 * k4 + 3] + s0[d0 + 3]) * inv;
                uint2 val;
                val.x = pk2bf(f0, f1);
                val.y = pk2bf(f2, f3);
                *(uint2*)(op + d0) = val;
            }
        }
    }
}

// ---------------------------------------------------------------------------
extern "C" void kernel_launch(void* const* d_in, const int* in_sizes, int n_in,
                              void* d_out, int out_size, void* d_ws, size_t ws_size,
                              hipStream_t stream)
{
    const float* x  = (const float*)d_in[0];
    const float* wq = (const float*)d_in[1];
    const float* wk = (const float*)d_in[2];
    const float* wv = (const float*)d_in[3];
    const float* wo = (const float*)d_in[4];
    float* out = (float*)d_out;

    const size_t SZ = (size_t)NROW * HD;               // 4M elements
    unsigned short* qb    = (unsigned short*)d_ws;     // 8 MB
    unsigned short* kb    = qb + SZ;                   // 8 MB
    unsigned short* vt    = kb + SZ;                   // 8 MB [(b,h),d,t]
    unsigned short* ob    = vt + SZ;                   // 8 MB
    unsigned short* xb    = ob + SZ;                   // 8 MB
    unsigned short* wqkvT = xb + SZ;                   // 6 MB [3072][1024]
    unsigned short* woT   = wqkvT + 3 * 1024 * 1024;   // 2 MB

    // prologue: x cast + 4 weight transposes, one launch
    prep<<<dim3(32, 32, 5), 256, 0, stream>>>(x, wq, wk, wv, wo, xb, wqkvT, woT);

    // fused QKV projection (+ RMSNorm/RoPE on q,k; V written transposed)
    gemm_qkv<<<dim3(24, 32), 256, 0, stream>>>(xb, wqkvT, qb, kb, vt);

    // deep-pipelined flash attention: 16 q-tiles x 16 bh, 512 thr
    flash_attn<<<dim3(16, 16), 512, 0, stream>>>(qb, kb, vt, ob);

    // output projection, 128x64 tiles -> 512 blocks
    gemm_out<<<dim3(16, 32), 256, 0, stream>>>(ob, woT, out);
}